// Round 1
// baseline (1972.574 us; speedup 1.0000x reference)
//
#include <hip/hip_runtime.h>

#define IN_C  256
#define HID   256
#define OUT_C 128

__global__ void k_deg_init(float* __restrict__ deg, int n) {
    int i = blockIdx.x * blockDim.x + threadIdx.x;
    if (i < n) deg[i] = 1.0f;   // self-loop contributes 1
}

__global__ void k_deg_count(const int* __restrict__ dst, float* __restrict__ deg, int e) {
    int i = blockIdx.x * blockDim.x + threadIdx.x;
    if (i < e) atomicAdd(&deg[dst[i]], 1.0f);
}

__global__ void k_dinv(const float* __restrict__ deg, float* __restrict__ dinv, int n) {
    int i = blockIdx.x * blockDim.x + threadIdx.x;
    if (i < n) dinv[i] = rsqrtf(deg[i]);   // deg >= 1 always (self-loops)
}

// t1 = x @ W1  (f32). Epilogue also writes out1 = t1*dinv^2 + b1 (self-loop + bias).
// 16 rows per 256-thread block; thread c owns output column c for all 16 rows.
__global__ __launch_bounds__(256) void k_gemm1(
    const float* __restrict__ x, const float* __restrict__ W1,
    const float* __restrict__ b1, const float* __restrict__ dinv,
    float* __restrict__ t1, float* __restrict__ out1, int n) {
    __shared__ float xs[16][IN_C];
    const int tid  = threadIdx.x;
    const int row0 = blockIdx.x * 16;
    #pragma unroll
    for (int r = 0; r < 16; ++r) {
        int i = row0 + r;
        xs[r][tid] = (i < n) ? x[(size_t)i * IN_C + tid] : 0.0f;
    }
    __syncthreads();
    float acc[16];
    #pragma unroll
    for (int r = 0; r < 16; ++r) acc[r] = 0.0f;
    #pragma unroll 4
    for (int k = 0; k < IN_C; ++k) {
        float w = W1[(size_t)k * HID + tid];
        #pragma unroll
        for (int r = 0; r < 16; ++r) acc[r] += xs[r][k] * w;
    }
    const float bias = b1[tid];
    #pragma unroll
    for (int r = 0; r < 16; ++r) {
        int i = row0 + r;
        if (i < n) {
            float di = dinv[i];
            float v = acc[r];
            t1[(size_t)i * HID + tid]   = v;
            out1[(size_t)i * HID + tid] = v * di * di + bias;
        }
    }
}

// Edge scatter for layer 1: out1[dst] += t1[src] * dinv[src]*dinv[dst].
// One 64-lane wave per edge; each lane handles a float4 (256 ch total).
__global__ void k_agg1(const float* __restrict__ t1, const float* __restrict__ dinv,
                       const int* __restrict__ src, const int* __restrict__ dst,
                       float* __restrict__ out1, int e) {
    long long g = (long long)blockIdx.x * blockDim.x + threadIdx.x;
    int eid  = (int)(g >> 6);
    int lane = (int)(g & 63);
    if (eid >= e) return;
    int s = src[eid], d = dst[eid];
    float w = dinv[s] * dinv[d];
    const float4 v = *(const float4*)(t1 + (size_t)s * HID + lane * 4);
    float* o = out1 + (size_t)d * HID + lane * 4;
    atomicAdd(o + 0, v.x * w);
    atomicAdd(o + 1, v.y * w);
    atomicAdd(o + 2, v.z * w);
    atomicAdd(o + 3, v.w * w);
}

// t2 = relu(out1) @ W2. Epilogue writes out = t2*dinv^2 + b2 (self-loop + bias).
// 8 rows per block of 256 threads: c = tid&127 (output col), g = tid>>7 owns 4 rows.
__global__ __launch_bounds__(256) void k_gemm2(
    const float* __restrict__ out1, const float* __restrict__ W2,
    const float* __restrict__ b2, const float* __restrict__ dinv,
    float* __restrict__ t2, float* __restrict__ out, int n) {
    __shared__ float hs[8][HID];
    const int tid  = threadIdx.x;
    const int row0 = blockIdx.x * 8;
    #pragma unroll
    for (int r = 0; r < 8; ++r) {
        int i = row0 + r;
        float v = (i < n) ? out1[(size_t)i * HID + tid] : 0.0f;
        hs[r][tid] = v > 0.0f ? v : 0.0f;   // fused ReLU
    }
    __syncthreads();
    const int c = tid & 127;
    const int grp = tid >> 7;
    float acc[4] = {0.f, 0.f, 0.f, 0.f};
    #pragma unroll 4
    for (int k = 0; k < HID; ++k) {
        float w = W2[(size_t)k * OUT_C + c];
        #pragma unroll
        for (int r = 0; r < 4; ++r) acc[r] += hs[grp * 4 + r][k] * w;
    }
    const float bias = b2[c];
    #pragma unroll
    for (int r = 0; r < 4; ++r) {
        int i = row0 + grp * 4 + r;
        if (i < n) {
            float di = dinv[i];
            float v = acc[r];
            t2[(size_t)i * OUT_C + c]  = v;
            out[(size_t)i * OUT_C + c] = v * di * di + bias;
        }
    }
}

// Edge scatter for layer 2 into d_out: 32 lanes per edge, float4 each (128 ch).
__global__ void k_agg2(const float* __restrict__ t2, const float* __restrict__ dinv,
                       const int* __restrict__ src, const int* __restrict__ dst,
                       float* __restrict__ out, int e) {
    long long g = (long long)blockIdx.x * blockDim.x + threadIdx.x;
    int eid  = (int)(g >> 5);
    int lane = (int)(g & 31);
    if (eid >= e) return;
    int s = src[eid], d = dst[eid];
    float w = dinv[s] * dinv[d];
    const float4 v = *(const float4*)(t2 + (size_t)s * OUT_C + lane * 4);
    float* o = out + (size_t)d * OUT_C + lane * 4;
    atomicAdd(o + 0, v.x * w);
    atomicAdd(o + 1, v.y * w);
    atomicAdd(o + 2, v.z * w);
    atomicAdd(o + 3, v.w * w);
}

extern "C" void kernel_launch(void* const* d_in, const int* in_sizes, int n_in,
                              void* d_out, int out_size, void* d_ws, size_t ws_size,
                              hipStream_t stream) {
    const float* x  = (const float*)d_in[0];
    const int*   ei = (const int*)d_in[1];
    const float* W1 = (const float*)d_in[2];
    const float* b1 = (const float*)d_in[3];
    const float* W2 = (const float*)d_in[4];
    const float* b2 = (const float*)d_in[5];
    float* out = (float*)d_out;

    const int n = in_sizes[0] / IN_C;   // 100000
    const int e = in_sizes[1] / 2;      // 300000
    const int* src = ei;
    const int* dst = ei + e;

    float* ws   = (float*)d_ws;
    float* deg  = ws;                         // [n]
    float* dinv = ws + n;                     // [n]
    float* t1   = ws + 2 * (size_t)n;         // [n*HID]
    float* out1 = t1 + (size_t)n * HID;       // [n*HID]
    float* t2   = t1;                         // reuse t1 (dead after agg1)

    k_deg_init<<<(n + 255) / 256, 256, 0, stream>>>(deg, n);
    k_deg_count<<<(e + 255) / 256, 256, 0, stream>>>(dst, deg, e);
    k_dinv<<<(n + 255) / 256, 256, 0, stream>>>(deg, dinv, n);

    k_gemm1<<<(n + 15) / 16, 256, 0, stream>>>(x, W1, b1, dinv, t1, out1, n);

    long long thr1 = (long long)e * 64;
    k_agg1<<<(unsigned)((thr1 + 255) / 256), 256, 0, stream>>>(t1, dinv, src, dst, out1, e);

    k_gemm2<<<(n + 7) / 8, 256, 0, stream>>>(out1, W2, b2, dinv, t2, out, n);

    long long thr2 = (long long)e * 32;
    k_agg2<<<(unsigned)((thr2 + 255) / 256), 256, 0, stream>>>(t2, dinv, src, dst, out, e);
}

// Round 2
// 585.959 us; speedup vs baseline: 3.3664x; 3.3664x over previous
//
#include <hip/hip_runtime.h>

#define IN_C  256
#define HID   256
#define OUT_C 128
#define SCAN_BS 1024

__global__ void k_zero_i(int* __restrict__ p, int n) {
    int i = blockIdx.x * blockDim.x + threadIdx.x;
    if (i < n) p[i] = 0;
}

__global__ void k_count(const int* __restrict__ dst, int* __restrict__ cnt, int e) {
    int i = blockIdx.x * blockDim.x + threadIdx.x;
    if (i < e) atomicAdd(&cnt[dst[i]], 1);
}

// Per-block exclusive scan (Hillis-Steele in LDS); writes block-local exclusive
// prefix into rs[i] and block total into bsum[block].
__global__ __launch_bounds__(SCAN_BS) void k_scan_block(
    const int* __restrict__ cnt, int* __restrict__ rs, int* __restrict__ bsum, int n) {
    __shared__ int s[SCAN_BS];
    const int tid = threadIdx.x;
    const int i = blockIdx.x * SCAN_BS + tid;
    int v = (i < n) ? cnt[i] : 0;
    s[tid] = v;
    __syncthreads();
    for (int off = 1; off < SCAN_BS; off <<= 1) {
        int t = (tid >= off) ? s[tid - off] : 0;
        __syncthreads();
        s[tid] += t;
        __syncthreads();
    }
    if (i < n) rs[i] = s[tid] - v;
    if (tid == SCAN_BS - 1) bsum[blockIdx.x] = s[tid];
}

// Exclusive scan of <=128 block sums, single block of 128.
__global__ void k_scan_sums(int* __restrict__ bsum, int nb) {
    __shared__ int s[128];
    const int tid = threadIdx.x;
    int v = (tid < nb) ? bsum[tid] : 0;
    s[tid] = v;
    __syncthreads();
    for (int off = 1; off < 128; off <<= 1) {
        int t = (tid >= off) ? s[tid - off] : 0;
        __syncthreads();
        s[tid] += t;
        __syncthreads();
    }
    if (tid < nb) bsum[tid] = s[tid] - v;
}

// rs[i] += bsum[block]; cursor = rs; dinv = rsqrt(deg+1)  (fused)
__global__ void k_scan_add(int* __restrict__ rs, int* __restrict__ cur,
                           const int* __restrict__ bsum, const int* __restrict__ cnt,
                           float* __restrict__ dinv, int n) {
    int i = blockIdx.x * blockDim.x + threadIdx.x;
    if (i < n) {
        int v = rs[i] + bsum[i >> 10];
        rs[i] = v;
        cur[i] = v;
        dinv[i] = rsqrtf((float)(cnt[i] + 1));   // +1 self-loop
    }
}

__global__ void k_fill(const int* __restrict__ src, const int* __restrict__ dst,
                       int* __restrict__ cur, int* __restrict__ csr, int e) {
    int i = blockIdx.x * blockDim.x + threadIdx.x;
    if (i < e) {
        int p = atomicAdd(&cur[dst[i]], 1);
        csr[p] = src[i];
    }
}

// t1 = x @ W1 (f32). 16 rows per 256-thread block; thread c owns column c.
__global__ __launch_bounds__(256) void k_gemm1(
    const float* __restrict__ x, const float* __restrict__ W1,
    float* __restrict__ t1, int n) {
    __shared__ float xs[16][IN_C];
    const int tid  = threadIdx.x;
    const int row0 = blockIdx.x * 16;
    #pragma unroll
    for (int r = 0; r < 16; ++r) {
        int i = row0 + r;
        xs[r][tid] = (i < n) ? x[(size_t)i * IN_C + tid] : 0.0f;
    }
    __syncthreads();
    float acc[16];
    #pragma unroll
    for (int r = 0; r < 16; ++r) acc[r] = 0.0f;
    #pragma unroll 4
    for (int k = 0; k < IN_C; ++k) {
        float w = W1[(size_t)k * HID + tid];
        #pragma unroll
        for (int r = 0; r < 16; ++r) acc[r] += xs[r][k] * w;
    }
    #pragma unroll
    for (int r = 0; r < 16; ++r) {
        int i = row0 + r;
        if (i < n) t1[(size_t)i * HID + tid] = acc[r];
    }
}

// Gather-aggregate layer 1: one wave per node, lane = float4 of 256 ch.
// out1 = relu( sum_edges dinv[s]*dinv[d]*t1[s] + dinv[d]^2*t1[d] + b1 )
__global__ __launch_bounds__(256) void k_agg1(
    const float* __restrict__ t1, const float* __restrict__ dinv,
    const int* __restrict__ rs, const int* __restrict__ cnt,
    const int* __restrict__ csr, const float* __restrict__ b1,
    float* __restrict__ out1, int n) {
    const int node = blockIdx.x * 4 + (threadIdx.x >> 6);
    if (node >= n) return;
    const int lane = threadIdx.x & 63;
    const float di = dinv[node];
    float4 v = *(const float4*)(t1 + (size_t)node * HID + lane * 4);
    const float w0 = di * di;
    float4 acc = {v.x * w0, v.y * w0, v.z * w0, v.w * w0};
    const int beg = rs[node], m = cnt[node];
    for (int j = 0; j < m; ++j) {
        int s = csr[beg + j];
        float w = dinv[s] * di;
        float4 u = *(const float4*)(t1 + (size_t)s * HID + lane * 4);
        acc.x += u.x * w; acc.y += u.y * w; acc.z += u.z * w; acc.w += u.w * w;
    }
    float4 bb = *(const float4*)(b1 + lane * 4);
    acc.x = fmaxf(acc.x + bb.x, 0.f);
    acc.y = fmaxf(acc.y + bb.y, 0.f);
    acc.z = fmaxf(acc.z + bb.z, 0.f);
    acc.w = fmaxf(acc.w + bb.w, 0.f);
    *(float4*)(out1 + (size_t)node * HID + lane * 4) = acc;
}

// t2 = out1 @ W2 (out1 already ReLU'd). 8 rows per 256-thread block.
__global__ __launch_bounds__(256) void k_gemm2(
    const float* __restrict__ out1, const float* __restrict__ W2,
    float* __restrict__ t2, int n) {
    __shared__ float hs[8][HID];
    const int tid  = threadIdx.x;
    const int row0 = blockIdx.x * 8;
    #pragma unroll
    for (int r = 0; r < 8; ++r) {
        int i = row0 + r;
        hs[r][tid] = (i < n) ? out1[(size_t)i * HID + tid] : 0.0f;
    }
    __syncthreads();
    const int c = tid & 127;
    const int grp = tid >> 7;
    float acc[4] = {0.f, 0.f, 0.f, 0.f};
    #pragma unroll 4
    for (int k = 0; k < HID; ++k) {
        float w = W2[(size_t)k * OUT_C + c];
        #pragma unroll
        for (int r = 0; r < 4; ++r) acc[r] += hs[grp * 4 + r][k] * w;
    }
    #pragma unroll
    for (int r = 0; r < 4; ++r) {
        int i = row0 + grp * 4 + r;
        if (i < n) t2[(size_t)i * OUT_C + c] = acc[r];
    }
}

// Gather-aggregate layer 2: one wave per node, lane = float2 of 128 ch.
// out = sum_edges w*t2[s] + dinv^2*t2[d] + b2
__global__ __launch_bounds__(256) void k_agg2(
    const float* __restrict__ t2, const float* __restrict__ dinv,
    const int* __restrict__ rs, const int* __restrict__ cnt,
    const int* __restrict__ csr, const float* __restrict__ b2,
    float* __restrict__ out, int n) {
    const int node = blockIdx.x * 4 + (threadIdx.x >> 6);
    if (node >= n) return;
    const int lane = threadIdx.x & 63;
    const float di = dinv[node];
    float2 v = *(const float2*)(t2 + (size_t)node * OUT_C + lane * 2);
    const float w0 = di * di;
    float2 acc = {v.x * w0, v.y * w0};
    const int beg = rs[node], m = cnt[node];
    for (int j = 0; j < m; ++j) {
        int s = csr[beg + j];
        float w = dinv[s] * di;
        float2 u = *(const float2*)(t2 + (size_t)s * OUT_C + lane * 2);
        acc.x += u.x * w; acc.y += u.y * w;
    }
    float2 bb = *(const float2*)(b2 + lane * 2);
    acc.x += bb.x;
    acc.y += bb.y;
    *(float2*)(out + (size_t)node * OUT_C + lane * 2) = acc;
}

extern "C" void kernel_launch(void* const* d_in, const int* in_sizes, int n_in,
                              void* d_out, int out_size, void* d_ws, size_t ws_size,
                              hipStream_t stream) {
    const float* x  = (const float*)d_in[0];
    const int*   ei = (const int*)d_in[1];
    const float* W1 = (const float*)d_in[2];
    const float* b1 = (const float*)d_in[3];
    const float* W2 = (const float*)d_in[4];
    const float* b2 = (const float*)d_in[5];
    float* out = (float*)d_out;

    const int n = in_sizes[0] / IN_C;   // 100000
    const int e = in_sizes[1] / 2;      // 300000
    const int* src = ei;
    const int* dst = ei + e;

    // workspace layout (all 4B elems; t1 offset is 16B-aligned: 4n+e+128 % 4 == 0)
    int*   cnt  = (int*)d_ws;                 // [n]
    int*   rs   = cnt + n;                    // [n]
    int*   cur  = rs + n;                     // [n]
    int*   bsum = cur + n;                    // [128]
    int*   csr  = bsum + 128;                 // [e]
    float* dinv = (float*)(csr + e);          // [n]
    float* t1   = dinv + n;                   // [n*HID]
    float* out1 = t1 + (size_t)n * HID;       // [n*HID]
    float* t2   = t1;                         // alias (t1 dead after agg1)

    const int nb = (n + SCAN_BS - 1) / SCAN_BS;   // 98 <= 128

    k_zero_i<<<(n + 255) / 256, 256, 0, stream>>>(cnt, n);
    k_count<<<(e + 255) / 256, 256, 0, stream>>>(dst, cnt, e);
    k_scan_block<<<nb, SCAN_BS, 0, stream>>>(cnt, rs, bsum, n);
    k_scan_sums<<<1, 128, 0, stream>>>(bsum, nb);
    k_scan_add<<<(n + 255) / 256, 256, 0, stream>>>(rs, cur, bsum, cnt, dinv, n);
    k_fill<<<(e + 255) / 256, 256, 0, stream>>>(src, dst, cur, csr, e);

    k_gemm1<<<(n + 15) / 16, 256, 0, stream>>>(x, W1, t1, n);
    k_agg1<<<(n + 3) / 4, 256, 0, stream>>>(t1, dinv, rs, cnt, csr, b1, out1, n);
    k_gemm2<<<(n + 7) / 8, 256, 0, stream>>>(out1, W2, t2, n);
    k_agg2<<<(n + 3) / 4, 256, 0, stream>>>(t2, dinv, rs, cnt, csr, b2, out, n);
}

// Round 3
// 225.350 us; speedup vs baseline: 8.7534x; 2.6002x over previous
//
#include <hip/hip_runtime.h>
#include <stdint.h>

#define IN_C  256
#define HID   256
#define OUT_C 128
#define SCAN_BS 1024

typedef __bf16 bf16x8 __attribute__((ext_vector_type(8)));
typedef float  f32x4  __attribute__((ext_vector_type(4)));
typedef unsigned short u16x8 __attribute__((ext_vector_type(8)));
typedef unsigned short u16x4 __attribute__((ext_vector_type(4)));
typedef unsigned short u16x2 __attribute__((ext_vector_type(2)));

static __device__ __forceinline__ unsigned short f2b(float f) {
    union { float f; uint32_t u; } v; v.f = f;
    uint32_t r = v.u + 0x7fffu + ((v.u >> 16) & 1u);
    return (unsigned short)(r >> 16);
}
static __device__ __forceinline__ float b2f(unsigned short b) {
    union { uint32_t u; float f; } v; v.u = ((uint32_t)b) << 16;
    return v.f;
}

// ---------------- CSR build (unchanged from R2) ----------------
__global__ void k_zero_i(int* __restrict__ p, int n) {
    int i = blockIdx.x * blockDim.x + threadIdx.x;
    if (i < n) p[i] = 0;
}

__global__ void k_count(const int* __restrict__ dst, int* __restrict__ cnt, int e) {
    int i = blockIdx.x * blockDim.x + threadIdx.x;
    if (i < e) atomicAdd(&cnt[dst[i]], 1);
}

__global__ __launch_bounds__(SCAN_BS) void k_scan_block(
    const int* __restrict__ cnt, int* __restrict__ rs, int* __restrict__ bsum, int n) {
    __shared__ int s[SCAN_BS];
    const int tid = threadIdx.x;
    const int i = blockIdx.x * SCAN_BS + tid;
    int v = (i < n) ? cnt[i] : 0;
    s[tid] = v;
    __syncthreads();
    for (int off = 1; off < SCAN_BS; off <<= 1) {
        int t = (tid >= off) ? s[tid - off] : 0;
        __syncthreads();
        s[tid] += t;
        __syncthreads();
    }
    if (i < n) rs[i] = s[tid] - v;
    if (tid == SCAN_BS - 1) bsum[blockIdx.x] = s[tid];
}

__global__ void k_scan_sums(int* __restrict__ bsum, int nb) {
    __shared__ int s[128];
    const int tid = threadIdx.x;
    int v = (tid < nb) ? bsum[tid] : 0;
    s[tid] = v;
    __syncthreads();
    for (int off = 1; off < 128; off <<= 1) {
        int t = (tid >= off) ? s[tid - off] : 0;
        __syncthreads();
        s[tid] += t;
        __syncthreads();
    }
    if (tid < nb) bsum[tid] = s[tid] - v;
}

__global__ void k_scan_add(int* __restrict__ rs, int* __restrict__ cur,
                           const int* __restrict__ bsum, const int* __restrict__ cnt,
                           float* __restrict__ dinv, int n) {
    int i = blockIdx.x * blockDim.x + threadIdx.x;
    if (i < n) {
        int v = rs[i] + bsum[i >> 10];
        rs[i] = v;
        cur[i] = v;
        dinv[i] = rsqrtf((float)(cnt[i] + 1));
    }
}

__global__ void k_fill(const int* __restrict__ src, const int* __restrict__ dst,
                       int* __restrict__ cur, int* __restrict__ csr, int e) {
    int i = blockIdx.x * blockDim.x + threadIdx.x;
    if (i < e) {
        int p = atomicAdd(&cur[dst[i]], 1);
        csr[p] = src[i];
    }
}

// Transposed bf16 weights: W1T[n][k] = W1[k][n] (256x256), W2T[n][k] = W2[k][n] (128x256)
__global__ void k_prep(const float* __restrict__ W1, const float* __restrict__ W2,
                       unsigned short* __restrict__ W1T, unsigned short* __restrict__ W2T) {
    int i = blockIdx.x * blockDim.x + threadIdx.x;
    if (i < 65536) W1T[i] = f2b(W1[(i & 255) * HID + (i >> 8)]);
    if (i < 32768) W2T[i] = f2b(W2[(i & 255) * OUT_C + (i >> 8)]);
}

// ---------------- GEMM1: t1[100000][256] bf16 = x(f32->bf16) @ W1 ----------------
// BM=128, BN=256 (full), BK=64. 512 threads = 8 waves (2x4), wave tile 64x64.
__global__ __launch_bounds__(512) void k_gemm1(
    const float* __restrict__ x, const unsigned short* __restrict__ W1T,
    unsigned short* __restrict__ t1, int n) {
    __shared__ __align__(16) unsigned short As[128 * 64];
    __shared__ __align__(16) unsigned short Bs[256 * 64];
    const int tid  = threadIdx.x;
    const int row0 = blockIdx.x * 128;
    const int wid = tid >> 6, lane = tid & 63;
    const int wm = wid >> 2, wn = wid & 3;
    const int lrow = lane & 15, lgrp = lane >> 4;

    f32x4 acc[4][4];
    #pragma unroll
    for (int i = 0; i < 4; ++i)
        #pragma unroll
        for (int j = 0; j < 4; ++j)
            acc[i][j] = (f32x4){0.f, 0.f, 0.f, 0.f};

    for (int kt = 0; kt < 4; ++kt) {
        // stage A (f32 -> bf16), 1024 chunks of 8, 2 per thread, XOR-swizzled
        #pragma unroll
        for (int i = 0; i < 2; ++i) {
            int chunk = tid + 512 * i;
            int r = chunk >> 3, c = chunk & 7;
            int grow = row0 + r;
            u16x8 pk = {0, 0, 0, 0, 0, 0, 0, 0};
            if (grow < n) {
                const float* sp = x + (size_t)grow * IN_C + kt * 64 + c * 8;
                float4 a = *(const float4*)sp;
                float4 b = *(const float4*)(sp + 4);
                pk[0] = f2b(a.x); pk[1] = f2b(a.y); pk[2] = f2b(a.z); pk[3] = f2b(a.w);
                pk[4] = f2b(b.x); pk[5] = f2b(b.y); pk[6] = f2b(b.z); pk[7] = f2b(b.w);
            }
            *(u16x8*)&As[r * 64 + ((c ^ (r & 7)) * 8)] = pk;
        }
        // stage B (already bf16), 2048 chunks, 4 per thread
        #pragma unroll
        for (int i = 0; i < 4; ++i) {
            int chunk = tid + 512 * i;
            int nn = chunk >> 3, c = chunk & 7;
            u16x8 pk = *(const u16x8*)&W1T[(size_t)nn * 256 + kt * 64 + c * 8];
            *(u16x8*)&Bs[nn * 64 + ((c ^ (nn & 7)) * 8)] = pk;
        }
        __syncthreads();
        #pragma unroll
        for (int kk = 0; kk < 2; ++kk) {
            const int cfrag = kk * 4 + lgrp;
            bf16x8 av[4], bv[4];
            #pragma unroll
            for (int mf = 0; mf < 4; ++mf) {
                int r = wm * 64 + mf * 16 + lrow;
                av[mf] = *(const bf16x8*)&As[r * 64 + ((cfrag ^ (r & 7)) * 8)];
            }
            #pragma unroll
            for (int nf = 0; nf < 4; ++nf) {
                int cc = wn * 64 + nf * 16 + lrow;
                bv[nf] = *(const bf16x8*)&Bs[cc * 64 + ((cfrag ^ (cc & 7)) * 8)];
            }
            #pragma unroll
            for (int mf = 0; mf < 4; ++mf)
                #pragma unroll
                for (int nf = 0; nf < 4; ++nf)
                    acc[mf][nf] = __builtin_amdgcn_mfma_f32_16x16x32_bf16(
                        av[mf], bv[nf], acc[mf][nf], 0, 0, 0);
        }
        __syncthreads();
    }
    // C layout: col = lane&15, row = (lane>>4)*4 + j  [m89/m91 verified]
    #pragma unroll
    for (int mf = 0; mf < 4; ++mf)
        #pragma unroll
        for (int j = 0; j < 4; ++j) {
            int grow = row0 + wm * 64 + mf * 16 + lgrp * 4 + j;
            if (grow < n) {
                #pragma unroll
                for (int nf = 0; nf < 4; ++nf) {
                    int col = wn * 64 + nf * 16 + lrow;
                    t1[(size_t)grow * HID + col] = f2b(acc[mf][nf][j]);
                }
            }
        }
}

// ---------------- agg1: out1 = relu(gather(t1) + b1), bf16 in / bf16 out ----------
__global__ __launch_bounds__(256) void k_agg1(
    const unsigned short* __restrict__ t1, const float* __restrict__ dinv,
    const int* __restrict__ rs, const int* __restrict__ cnt,
    const int* __restrict__ csr, const float* __restrict__ b1,
    unsigned short* __restrict__ out1, int n) {
    const int node = blockIdx.x * 4 + (threadIdx.x >> 6);
    if (node >= n) return;
    const int lane = threadIdx.x & 63;
    const float di = dinv[node];
    u16x4 v = *(const u16x4*)&t1[(size_t)node * HID + lane * 4];
    const float w0 = di * di;
    float a0 = b2f(v[0]) * w0, a1 = b2f(v[1]) * w0, a2 = b2f(v[2]) * w0, a3 = b2f(v[3]) * w0;
    const int beg = rs[node], m = cnt[node];
    for (int j = 0; j < m; ++j) {
        int s = csr[beg + j];
        float w = dinv[s] * di;
        u16x4 u = *(const u16x4*)&t1[(size_t)s * HID + lane * 4];
        a0 += b2f(u[0]) * w; a1 += b2f(u[1]) * w; a2 += b2f(u[2]) * w; a3 += b2f(u[3]) * w;
    }
    float4 bb = *(const float4*)(b1 + lane * 4);
    u16x4 o;
    o[0] = f2b(fmaxf(a0 + bb.x, 0.f));
    o[1] = f2b(fmaxf(a1 + bb.y, 0.f));
    o[2] = f2b(fmaxf(a2 + bb.z, 0.f));
    o[3] = f2b(fmaxf(a3 + bb.w, 0.f));
    *(u16x4*)&out1[(size_t)node * HID + lane * 4] = o;
}

// ---------------- GEMM2: t2[100000][128] bf16 = out1(bf16) @ W2 -------------------
// BM=128, BN=128, BK=64. 256 threads = 4 waves (2x2), wave tile 64x64.
__global__ __launch_bounds__(256) void k_gemm2(
    const unsigned short* __restrict__ out1, const unsigned short* __restrict__ W2T,
    unsigned short* __restrict__ t2, int n) {
    __shared__ __align__(16) unsigned short As[128 * 64];
    __shared__ __align__(16) unsigned short Bs[128 * 64];
    const int tid  = threadIdx.x;
    const int row0 = blockIdx.x * 128;
    const int wid = tid >> 6, lane = tid & 63;
    const int wm = wid >> 1, wn = wid & 1;
    const int lrow = lane & 15, lgrp = lane >> 4;

    f32x4 acc[4][4];
    #pragma unroll
    for (int i = 0; i < 4; ++i)
        #pragma unroll
        for (int j = 0; j < 4; ++j)
            acc[i][j] = (f32x4){0.f, 0.f, 0.f, 0.f};

    for (int kt = 0; kt < 4; ++kt) {
        #pragma unroll
        for (int i = 0; i < 4; ++i) {
            int chunk = tid + 256 * i;
            int r = chunk >> 3, c = chunk & 7;
            int grow = row0 + r;
            u16x8 pk = {0, 0, 0, 0, 0, 0, 0, 0};
            if (grow < n)
                pk = *(const u16x8*)&out1[(size_t)grow * HID + kt * 64 + c * 8];
            *(u16x8*)&As[r * 64 + ((c ^ (r & 7)) * 8)] = pk;
        }
        #pragma unroll
        for (int i = 0; i < 4; ++i) {
            int chunk = tid + 256 * i;
            int nn = chunk >> 3, c = chunk & 7;
            u16x8 pk = *(const u16x8*)&W2T[(size_t)nn * 256 + kt * 64 + c * 8];
            *(u16x8*)&Bs[nn * 64 + ((c ^ (nn & 7)) * 8)] = pk;
        }
        __syncthreads();
        #pragma unroll
        for (int kk = 0; kk < 2; ++kk) {
            const int cfrag = kk * 4 + lgrp;
            bf16x8 av[4], bv[4];
            #pragma unroll
            for (int mf = 0; mf < 4; ++mf) {
                int r = wm * 64 + mf * 16 + lrow;
                av[mf] = *(const bf16x8*)&As[r * 64 + ((cfrag ^ (r & 7)) * 8)];
            }
            #pragma unroll
            for (int nf = 0; nf < 4; ++nf) {
                int cc = wn * 64 + nf * 16 + lrow;
                bv[nf] = *(const bf16x8*)&Bs[cc * 64 + ((cfrag ^ (cc & 7)) * 8)];
            }
            #pragma unroll
            for (int mf = 0; mf < 4; ++mf)
                #pragma unroll
                for (int nf = 0; nf < 4; ++nf)
                    acc[mf][nf] = __builtin_amdgcn_mfma_f32_16x16x32_bf16(
                        av[mf], bv[nf], acc[mf][nf], 0, 0, 0);
        }
        __syncthreads();
    }
    #pragma unroll
    for (int mf = 0; mf < 4; ++mf)
        #pragma unroll
        for (int j = 0; j < 4; ++j) {
            int grow = row0 + wm * 64 + mf * 16 + lgrp * 4 + j;
            if (grow < n) {
                #pragma unroll
                for (int nf = 0; nf < 4; ++nf) {
                    int col = wn * 64 + nf * 16 + lrow;
                    t2[(size_t)grow * OUT_C + col] = f2b(acc[mf][nf][j]);
                }
            }
        }
}

// ---------------- agg2: out(f32) = gather(t2) + b2 --------------------------------
__global__ __launch_bounds__(256) void k_agg2(
    const unsigned short* __restrict__ t2, const float* __restrict__ dinv,
    const int* __restrict__ rs, const int* __restrict__ cnt,
    const int* __restrict__ csr, const float* __restrict__ b2,
    float* __restrict__ out, int n) {
    const int node = blockIdx.x * 4 + (threadIdx.x >> 6);
    if (node >= n) return;
    const int lane = threadIdx.x & 63;
    const float di = dinv[node];
    u16x2 v = *(const u16x2*)&t2[(size_t)node * OUT_C + lane * 2];
    const float w0 = di * di;
    float a0 = b2f(v[0]) * w0, a1 = b2f(v[1]) * w0;
    const int beg = rs[node], m = cnt[node];
    for (int j = 0; j < m; ++j) {
        int s = csr[beg + j];
        float w = dinv[s] * di;
        u16x2 u = *(const u16x2*)&t2[(size_t)s * OUT_C + lane * 2];
        a0 += b2f(u[0]) * w; a1 += b2f(u[1]) * w;
    }
    float2 bb = *(const float2*)(b2 + lane * 2);
    float2 o = {a0 + bb.x, a1 + bb.y};
    *(float2*)&out[(size_t)node * OUT_C + lane * 2] = o;
}

extern "C" void kernel_launch(void* const* d_in, const int* in_sizes, int n_in,
                              void* d_out, int out_size, void* d_ws, size_t ws_size,
                              hipStream_t stream) {
    const float* x  = (const float*)d_in[0];
    const int*   ei = (const int*)d_in[1];
    const float* W1 = (const float*)d_in[2];
    const float* b1 = (const float*)d_in[3];
    const float* W2 = (const float*)d_in[4];
    const float* b2 = (const float*)d_in[5];
    float* out = (float*)d_out;

    const int n = in_sizes[0] / IN_C;   // 100000
    const int e = in_sizes[1] / 2;      // 300000
    const int* src = ei;
    const int* dst = ei + e;

    // workspace layout (4B words)
    int*   cnt  = (int*)d_ws;                       // [n]
    int*   rs   = cnt + n;                          // [n]
    int*   cur  = rs + n;                           // [n]
    int*   bsum = cur + n;                          // [128]
    int*   csr  = bsum + 128;                       // [e]
    float* dinv = (float*)(csr + e);                // [n]
    unsigned short* W1T = (unsigned short*)(dinv + n);   // [256*256]
    unsigned short* W2T = W1T + 65536;                   // [128*256]
    unsigned short* t1  = W2T + 32768;                   // [n*HID] bf16 (16B-aligned)
    unsigned short* out1 = t1 + (size_t)n * HID;         // [n*HID] bf16
    unsigned short* t2  = t1;                            // alias (t1 dead after agg1)

    const int nb = (n + SCAN_BS - 1) / SCAN_BS;

    k_zero_i<<<(n + 255) / 256, 256, 0, stream>>>(cnt, n);
    k_count<<<(e + 255) / 256, 256, 0, stream>>>(dst, cnt, e);
    k_scan_block<<<nb, SCAN_BS, 0, stream>>>(cnt, rs, bsum, n);
    k_scan_sums<<<1, 128, 0, stream>>>(bsum, nb);
    k_scan_add<<<(n + 255) / 256, 256, 0, stream>>>(rs, cur, bsum, cnt, dinv, n);
    k_fill<<<(e + 255) / 256, 256, 0, stream>>>(src, dst, cur, csr, e);
    k_prep<<<256, 256, 0, stream>>>(W1, W2, W1T, W2T);

    const int mb = (n + 127) / 128;   // 782
    k_gemm1<<<mb, 512, 0, stream>>>(x, W1T, t1, n);
    k_agg1<<<(n + 3) / 4, 256, 0, stream>>>(t1, dinv, rs, cnt, csr, b1, out1, n);
    k_gemm2<<<mb, 256, 0, stream>>>(out1, W2T, t2, n);
    k_agg2<<<(n + 3) / 4, 256, 0, stream>>>(t2, dinv, rs, cnt, csr, b2, out, n);
}